// Round 10
// baseline (124.736 us; speedup 1.0000x reference)
//
#include <hip/hip_runtime.h>

// Problem geometry: B=64, A=9, H=W=128, C=1000
// N4 = 64*9*4096 = 2,359,296 float4 units over (B,A,H,W).
// Plane = 4096 float4. Block b: plane ba = b>>2, quarter sub = b&3.
// Each block owns 1024 f4 (16 KB) of each of the 10 planes; 4 f4/thread.
//
// Round-10 experiment (H4: DRAM row locality): read TWO streams at a
// time in long contiguous bursts, instead of 10 interleaved streams.
//   phase 0 : m + objects   (2 streams, 8 asm loads, one vmcnt drain)
//   phase c : l_c + gt_c    (2 streams, 8 asm loads, one vmcnt drain)
// m stays register-resident (16 VGPR) across all phases.
static constexpr int HW4 = 4096;
static constexpr float LOGCLAMP = -100.0f;

typedef float v4f __attribute__((ext_vector_type(4)));

// ws layout: ws[0]=no_obj_confi, ws[1]=obj_confi, ws[2]=obj_coor, ws[3]=img_class

// Inline-asm load: dwordx4 from SGPR base + 32-bit VGPR byte offset.
// volatile => issue order preserved; we own the waits (vmcnt + sched_barrier).
__device__ __forceinline__ v4f gld(unsigned voff, const void* base) {
    v4f d;
    asm volatile("global_load_dwordx4 %0, %1, %2"
                 : "=v"(d)
                 : "v"(voff), "s"(base));
    return d;
}

__device__ __forceinline__ void conf_acc(const v4f o, const v4f m,
                                         float& s_noobj, float& s_obj) {
    #pragma unroll
    for (int c = 0; c < 4; ++c) {
        const float lp  = fmaxf(__logf(o[c]),        LOGCLAMP);
        const float l1m = fmaxf(__logf(1.0f - o[c]), LOGCLAMP);
        s_noobj -= (1.0f - m[c]) * l1m;
        s_obj   -= m[c] * lp;
    }
}

__device__ __forceinline__ void coor_acc(const v4f l, const v4f g, const v4f m,
                                         float& s_coor) {
    #pragma unroll
    for (int c = 0; c < 4; ++c) {
        const float d = l[c] - g[c];
        s_coor += m[c] * (d * d);
    }
}

__global__ __launch_bounds__(256) void main_loss_kernel(
    const float4* __restrict__ objects,   // (576, 4096)
    const float4* __restrict__ locs,      // (576, 4, 4096)
    const float4* __restrict__ gt,        // (576, 5, 4096)
    float* __restrict__ ws)
{
    const int b   = blockIdx.x;
    const int tid = threadIdx.x;          // 0..255

    const int ba  = b >> 2;               // plane index (0..575)
    const int sub = b & 3;                 // quarter of the plane

    const float4* gtb = gt   + ba * 5 * HW4 + sub * 1024;
    const float4* lcb = locs + ba * 4 * HW4 + sub * 1024;
    const void* pO = (const void*)(objects + ba * HW4 + sub * 1024);
    const void* pM = (const void*)gtb;

    const unsigned v0 = (unsigned)tid * 16u;   // byte offset of this thread

    float s_noobj = 0.0f, s_obj = 0.0f, s_coor = 0.0f;

    // ---- phase 0: m + objects (2 contiguous 16 KB streams per block) ----
    v4f m0 = gld(v0 + 0u * 4096u, pM);
    v4f m1 = gld(v0 + 1u * 4096u, pM);
    v4f m2 = gld(v0 + 2u * 4096u, pM);
    v4f m3 = gld(v0 + 3u * 4096u, pM);
    v4f o0 = gld(v0 + 0u * 4096u, pO);
    v4f o1 = gld(v0 + 1u * 4096u, pO);
    v4f o2 = gld(v0 + 2u * 4096u, pO);
    v4f o3 = gld(v0 + 3u * 4096u, pO);

    asm volatile("s_waitcnt vmcnt(0)" ::: "memory");
    __builtin_amdgcn_sched_barrier(0);

    conf_acc(o0, m0, s_noobj, s_obj);
    conf_acc(o1, m1, s_noobj, s_obj);
    conf_acc(o2, m2, s_noobj, s_obj);
    conf_acc(o3, m3, s_noobj, s_obj);

    // ---- coordinate phases: l_c + gt_c (2 streams at a time) ----
    #pragma unroll
    for (int c = 0; c < 4; ++c) {
        const void* pL = (const void*)(lcb + c * HW4);
        const void* pG = (const void*)(gtb + (c + 1) * HW4);

        v4f L0 = gld(v0 + 0u * 4096u, pL);
        v4f L1 = gld(v0 + 1u * 4096u, pL);
        v4f L2 = gld(v0 + 2u * 4096u, pL);
        v4f L3 = gld(v0 + 3u * 4096u, pL);
        v4f G0 = gld(v0 + 0u * 4096u, pG);
        v4f G1 = gld(v0 + 1u * 4096u, pG);
        v4f G2 = gld(v0 + 2u * 4096u, pG);
        v4f G3 = gld(v0 + 3u * 4096u, pG);

        asm volatile("s_waitcnt vmcnt(0)" ::: "memory");
        __builtin_amdgcn_sched_barrier(0);

        coor_acc(L0, G0, m0, s_coor);
        coor_acc(L1, G1, m1, s_coor);
        coor_acc(L2, G2, m2, s_coor);
        coor_acc(L3, G3, m3, s_coor);
    }

    // wave64 reduce all three sums
    #pragma unroll
    for (int off = 32; off > 0; off >>= 1) {
        s_noobj += __shfl_down(s_noobj, off, 64);
        s_obj   += __shfl_down(s_obj,   off, 64);
        s_coor  += __shfl_down(s_coor,  off, 64);
    }

    __shared__ float red[3][4];
    const int lane = tid & 63;
    const int wid  = tid >> 6;
    if (lane == 0) {
        red[0][wid] = s_noobj;
        red[1][wid] = s_obj;
        red[2][wid] = s_coor;
    }
    __syncthreads();
    if (tid == 0) {
        atomicAdd(&ws[0], red[0][0] + red[0][1] + red[0][2] + red[0][3]);
        atomicAdd(&ws[1], red[1][0] + red[1][1] + red[1][2] + red[1][3]);
        atomicAdd(&ws[2], red[2][0] + red[2][1] + red[2][2] + red[2][3]);
    }
}

// img_class_loss: one block per batch row, C=1000
__global__ __launch_bounds__(256) void class_loss_kernel(
    const float* __restrict__ scores,   // (64, 1000)
    const int*   __restrict__ label,    // (64,)
    float* __restrict__ ws)
{
    const int b = blockIdx.x;
    const float* row = scores + b * 1000;

    float mx = -INFINITY;
    for (int i = threadIdx.x; i < 1000; i += 256) mx = fmaxf(mx, row[i]);
    #pragma unroll
    for (int off = 32; off > 0; off >>= 1) mx = fmaxf(mx, __shfl_down(mx, off, 64));

    __shared__ float smax[4];
    const int lane = threadIdx.x & 63;
    const int wid  = threadIdx.x >> 6;
    if (lane == 0) smax[wid] = mx;
    __syncthreads();
    mx = fmaxf(fmaxf(smax[0], smax[1]), fmaxf(smax[2], smax[3]));

    float se = 0.0f;
    for (int i = threadIdx.x; i < 1000; i += 256) se += __expf(row[i] - mx);
    #pragma unroll
    for (int off = 32; off > 0; off >>= 1) se += __shfl_down(se, off, 64);

    __shared__ float ssum[4];
    if (lane == 0) ssum[wid] = se;
    __syncthreads();
    if (threadIdx.x == 0) {
        se = ssum[0] + ssum[1] + ssum[2] + ssum[3];
        const float logp = row[label[b]] - mx - __logf(se);
        atomicAdd(&ws[3], -logp * (1.0f / 64.0f));   // mean over B
    }
}

__global__ void finalize_kernel(const float* __restrict__ ws, float* __restrict__ out)
{
    // IMG_CLASS_WEIGHT*class + (0.5*noobj + 1.0*obj + 5.0*coor)/B
    out[0] = ws[3] + (0.5f * ws[0] + 1.0f * ws[1] + 5.0f * ws[2]) * (1.0f / 64.0f);
}

extern "C" void kernel_launch(void* const* d_in, const int* in_sizes, int n_in,
                              void* d_out, int out_size, void* d_ws, size_t ws_size,
                              hipStream_t stream)
{
    const float* objects = (const float*)d_in[0];   // (64,9,128,128)
    const float* scores  = (const float*)d_in[1];   // (64,1000)
    const float* locs    = (const float*)d_in[2];   // (64,9,4,128,128)
    const int*   label   = (const int*)d_in[3];     // (64,)
    const float* gt      = (const float*)d_in[4];   // (64,9,5,128,128)
    float* ws  = (float*)d_ws;
    float* out = (float*)d_out;

    hipMemsetAsync(ws, 0, 4 * sizeof(float), stream);

    main_loss_kernel<<<2304, 256, 0, stream>>>(
        (const float4*)objects, (const float4*)locs, (const float4*)gt, ws);
    class_loss_kernel<<<64, 256, 0, stream>>>(scores, label, ws);
    finalize_kernel<<<1, 1, 0, stream>>>(ws, out);
}

// Round 11
// 120.917 us; speedup vs baseline: 1.0316x; 1.0316x over previous
//
#include <hip/hip_runtime.h>

// Problem geometry: B=64, A=9, H=W=128, C=1000
// N4 = 64*9*4096 = 2,359,296 float4 units over (B,A,H,W).
// Plane = 4096 float4. Block b: plane ba = b>>2, quarter sub = b&3
// (1024 f4 per plane). 4 rounds x CHUNK=256 f4 = exact cover.
// 2304 blocks x 256 threads.
//
// Best-measured structure (round 9, 121.0 us):
//   locs (151 MB)        -> __builtin_nontemporal_load (VGPR path)
//   objects+gt (226 MB)  -> global_load_lds staged (zero data-VGPR cost)
// Each wave stages and reads ONLY its own 64-lane LDS slice => no barriers.
// Empirical ceiling: ~24 G 128B-line-requests/s => ~3.1 TB/s pure-read.
static constexpr int HW4    = 4096;
static constexpr int CHUNK  = 256;
static constexpr int ROUNDS = 4;
static constexpr float LOGCLAMP = -100.0f;

typedef float v4f __attribute__((ext_vector_type(4)));

// ws layout: ws[0]=no_obj_confi, ws[1]=obj_confi, ws[2]=obj_coor, ws[3]=img_class

// Async HBM->LDS, 16 B per lane; zero data-VGPR cost; counted by vmcnt.
__device__ __forceinline__ void stage16(const float4* g, float4* l) {
    __builtin_amdgcn_global_load_lds(
        (const __attribute__((address_space(1))) void*)g,
        (__attribute__((address_space(3))) void*)l,
        16, 0, 0);
}

__global__ __launch_bounds__(256) void main_loss_kernel(
    const float4* __restrict__ objects,   // (576, 4096)
    const float4* __restrict__ locs,      // (576, 4, 4096)
    const float4* __restrict__ gt,        // (576, 5, 4096)
    float* __restrict__ ws)
{
    // 6 staged planes x 256 float4 = 24 KB: o, m, g0..g3
    __shared__ float4 lds[6][CHUNK];

    const int b   = blockIdx.x;
    const int tid = threadIdx.x;          // 0..255
    const int wb  = tid & ~63;            // wave's slice base

    const int ba  = b >> 2;               // plane index (0..575)
    const int sub = b & 3;                 // quarter of the plane

    const float4* pO  = objects + ba * HW4     + sub * 1024;
    const float4* gtb = gt      + ba * 5 * HW4 + sub * 1024;
    const v4f*    lcb = (const v4f*)(locs + ba * 4 * HW4 + sub * 1024);

    float s_noobj = 0.0f, s_obj = 0.0f, s_coor = 0.0f;

    #pragma unroll 1
    for (int r = 0; r < ROUNDS; ++r) {
        const int off = r * CHUNK + tid;

        // ---- nt loads of locs (VGPR path, no cache alloc) ----
        const v4f L0 = __builtin_nontemporal_load(lcb + 0 * HW4 + off);
        const v4f L1 = __builtin_nontemporal_load(lcb + 1 * HW4 + off);
        const v4f L2 = __builtin_nontemporal_load(lcb + 2 * HW4 + off);
        const v4f L3 = __builtin_nontemporal_load(lcb + 3 * HW4 + off);

        // ---- staged path: objects + gt, 6 planes ----
        stage16(pO  + off,           &lds[0][wb]);
        stage16(gtb + 0 * HW4 + off, &lds[1][wb]);
        stage16(gtb + 1 * HW4 + off, &lds[2][wb]);
        stage16(gtb + 2 * HW4 + off, &lds[3][wb]);
        stage16(gtb + 3 * HW4 + off, &lds[4][wb]);
        stage16(gtb + 4 * HW4 + off, &lds[5][wb]);

        // All 10 streams of this round are now in flight together.
        asm volatile("s_waitcnt vmcnt(0)" ::: "memory");
        __builtin_amdgcn_sched_barrier(0);

        // Own-slice LDS reads (contiguous ds_read_b128, conflict-free).
        const float4 o  = lds[0][tid];
        const float4 m  = lds[1][tid];
        const float4 g0 = lds[2][tid];
        const float4 g1 = lds[3][tid];
        const float4 g2 = lds[4][tid];
        const float4 g3 = lds[5][tid];

        {
            const float d0 = L0[0] - g0.x, d1 = L1[0] - g1.x,
                        d2 = L2[0] - g2.x, d3 = L3[0] - g3.x;
            const float sq = d0 * d0 + d1 * d1 + d2 * d2 + d3 * d3;
            const float lp  = fmaxf(__logf(o.x),        LOGCLAMP);
            const float l1m = fmaxf(__logf(1.0f - o.x), LOGCLAMP);
            s_noobj -= (1.0f - m.x) * l1m;
            s_obj   -= m.x * lp;
            s_coor  += m.x * sq;
        }
        {
            const float d0 = L0[1] - g0.y, d1 = L1[1] - g1.y,
                        d2 = L2[1] - g2.y, d3 = L3[1] - g3.y;
            const float sq = d0 * d0 + d1 * d1 + d2 * d2 + d3 * d3;
            const float lp  = fmaxf(__logf(o.y),        LOGCLAMP);
            const float l1m = fmaxf(__logf(1.0f - o.y), LOGCLAMP);
            s_noobj -= (1.0f - m.y) * l1m;
            s_obj   -= m.y * lp;
            s_coor  += m.y * sq;
        }
        {
            const float d0 = L0[2] - g0.z, d1 = L1[2] - g1.z,
                        d2 = L2[2] - g2.z, d3 = L3[2] - g3.z;
            const float sq = d0 * d0 + d1 * d1 + d2 * d2 + d3 * d3;
            const float lp  = fmaxf(__logf(o.z),        LOGCLAMP);
            const float l1m = fmaxf(__logf(1.0f - o.z), LOGCLAMP);
            s_noobj -= (1.0f - m.z) * l1m;
            s_obj   -= m.z * lp;
            s_coor  += m.z * sq;
        }
        {
            const float d0 = L0[3] - g0.w, d1 = L1[3] - g1.w,
                        d2 = L2[3] - g2.w, d3 = L3[3] - g3.w;
            const float sq = d0 * d0 + d1 * d1 + d2 * d2 + d3 * d3;
            const float lp  = fmaxf(__logf(o.w),        LOGCLAMP);
            const float l1m = fmaxf(__logf(1.0f - o.w), LOGCLAMP);
            s_noobj -= (1.0f - m.w) * l1m;
            s_obj   -= m.w * lp;
            s_coor  += m.w * sq;
        }
    }

    // wave64 reduce all three sums
    #pragma unroll
    for (int off = 32; off > 0; off >>= 1) {
        s_noobj += __shfl_down(s_noobj, off, 64);
        s_obj   += __shfl_down(s_obj,   off, 64);
        s_coor  += __shfl_down(s_coor,  off, 64);
    }

    __shared__ float red[3][4];
    const int lane = tid & 63;
    const int wid  = tid >> 6;
    if (lane == 0) {
        red[0][wid] = s_noobj;
        red[1][wid] = s_obj;
        red[2][wid] = s_coor;
    }
    __syncthreads();
    if (tid == 0) {
        atomicAdd(&ws[0], red[0][0] + red[0][1] + red[0][2] + red[0][3]);
        atomicAdd(&ws[1], red[1][0] + red[1][1] + red[1][2] + red[1][3]);
        atomicAdd(&ws[2], red[2][0] + red[2][1] + red[2][2] + red[2][3]);
    }
}

// img_class_loss: one block per batch row, C=1000
__global__ __launch_bounds__(256) void class_loss_kernel(
    const float* __restrict__ scores,   // (64, 1000)
    const int*   __restrict__ label,    // (64,)
    float* __restrict__ ws)
{
    const int b = blockIdx.x;
    const float* row = scores + b * 1000;

    float mx = -INFINITY;
    for (int i = threadIdx.x; i < 1000; i += 256) mx = fmaxf(mx, row[i]);
    #pragma unroll
    for (int off = 32; off > 0; off >>= 1) mx = fmaxf(mx, __shfl_down(mx, off, 64));

    __shared__ float smax[4];
    const int lane = threadIdx.x & 63;
    const int wid  = threadIdx.x >> 6;
    if (lane == 0) smax[wid] = mx;
    __syncthreads();
    mx = fmaxf(fmaxf(smax[0], smax[1]), fmaxf(smax[2], smax[3]));

    float se = 0.0f;
    for (int i = threadIdx.x; i < 1000; i += 256) se += __expf(row[i] - mx);
    #pragma unroll
    for (int off = 32; off > 0; off >>= 1) se += __shfl_down(se, off, 64);

    __shared__ float ssum[4];
    if (lane == 0) ssum[wid] = se;
    __syncthreads();
    if (threadIdx.x == 0) {
        se = ssum[0] + ssum[1] + ssum[2] + ssum[3];
        const float logp = row[label[b]] - mx - __logf(se);
        atomicAdd(&ws[3], -logp * (1.0f / 64.0f));   // mean over B
    }
}

__global__ void finalize_kernel(const float* __restrict__ ws, float* __restrict__ out)
{
    // IMG_CLASS_WEIGHT*class + (0.5*noobj + 1.0*obj + 5.0*coor)/B
    out[0] = ws[3] + (0.5f * ws[0] + 1.0f * ws[1] + 5.0f * ws[2]) * (1.0f / 64.0f);
}

extern "C" void kernel_launch(void* const* d_in, const int* in_sizes, int n_in,
                              void* d_out, int out_size, void* d_ws, size_t ws_size,
                              hipStream_t stream)
{
    const float* objects = (const float*)d_in[0];   // (64,9,128,128)
    const float* scores  = (const float*)d_in[1];   // (64,1000)
    const float* locs    = (const float*)d_in[2];   // (64,9,4,128,128)
    const int*   label   = (const int*)d_in[3];     // (64,)
    const float* gt      = (const float*)d_in[4];   // (64,9,5,128,128)
    float* ws  = (float*)d_ws;
    float* out = (float*)d_out;

    hipMemsetAsync(ws, 0, 4 * sizeof(float), stream);

    main_loss_kernel<<<2304, 256, 0, stream>>>(
        (const float4*)objects, (const float4*)locs, (const float4*)gt, ws);
    class_loss_kernel<<<64, 256, 0, stream>>>(scores, label, ws);
    finalize_kernel<<<1, 1, 0, stream>>>(ws, out);
}